// Round 12
// baseline (292.857 us; speedup 1.0000x reference)
//
#include <hip/hip_runtime.h>

#define N_NODES 4096
#define N_EDGES 131072
#define DIM     256
#define HEADS   8
#define HDIM    32
#define MAXDEG  320
#define MAXDEGP 321   // (321h+t)%32 = (h+t)%32 -> 8 heads hit distinct banks

typedef unsigned short u16;
typedef unsigned int   u32;

using f32x4  = __attribute__((ext_vector_type(4))) float;
using bf16x8 = __attribute__((ext_vector_type(8))) short;
using u16x4  = __attribute__((ext_vector_type(4))) unsigned short;
using u16x8  = __attribute__((ext_vector_type(8))) unsigned short;

__device__ __forceinline__ u16 f2bf(float f) {
  u32 u = __float_as_uint(f);
  u += 0x7fffu + ((u >> 16) & 1u);   // RNE
  return (u16)(u >> 16);
}

__device__ __forceinline__ float dot4(float4 a, float4 b) {
  return a.x * b.x + a.y * b.y + a.z * b.z + a.w * b.w;
}

// ---------------------------------------------------------------------------
// Weight prep
// ---------------------------------------------------------------------------
__global__ __launch_bounds__(256) void prep_w_k(
    const float* __restrict__ Wq, const float* __restrict__ Wk,
    const float* __restrict__ Wv, const float* __restrict__ Wi,
    const float* __restrict__ We, const float* __restrict__ Wo,
    const float* __restrict__ bq, const float* __restrict__ bk,
    const float* __restrict__ bv, const float* __restrict__ bi,
    u16* __restrict__ WcatT, u16* __restrict__ WeT, u16* __restrict__ WoT,
    float* __restrict__ bcat)
{
  int n = blockIdx.x;
  int k = threadIdx.x;
  if (n < 1024) {
    const float* W = (n < 256) ? Wq : (n < 512) ? Wk : (n < 768) ? Wv : Wi;
    int nn = n & 255;
    WcatT[(size_t)n * 256 + k] = f2bf(W[(size_t)k * 256 + nn]);
    if (k == 0) {
      const float* b = (n < 256) ? bq : (n < 512) ? bk : (n < 768) ? bv : bi;
      bcat[n] = b[nn];
    }
  } else if (n < 1280) {
    int nn = n - 1024;
    WeT[(size_t)nn * 256 + k] = f2bf(We[(size_t)k * 256 + nn]);
  } else {
    int nn = n - 1280;
    WoT[(size_t)nn * 256 + k] = f2bf(Wo[(size_t)k * 256 + nn]);
  }
}

// ---------------------------------------------------------------------------
// 128x128 GEMM (proven 88us structure): C = A(fp32) @ B + bias, BT = B^T bf16.
// ---------------------------------------------------------------------------
__global__ __launch_bounds__(256) void gemm3_k(
    const float* __restrict__ Afp, const u16* __restrict__ BT,
    const float* __restrict__ bias, float* __restrict__ C, int Nn)
{
  __shared__ u16 As[2][128 * 32];
  __shared__ u16 Bs[2][128 * 32];
  const int n0 = blockIdx.x * 128;
  const int m0 = blockIdx.y * 128;
  const int tid = threadIdx.x;
  const int w = tid >> 6, l = tid & 63;
  const int wr = w >> 1, wc = w & 1;
  const int fr = l & 15, hi = l >> 4;

  float4 pa[4];
  u16x8  pb[2];
  f32x4  acc[4][4] = {};

  auto loadstep = [&](int kt) {
#pragma unroll
    for (int i = 0; i < 4; ++i) {
      int j = tid + 256 * i;
      pa[i] = *(const float4*)(Afp + (size_t)(m0 + (j >> 3)) * 256 + kt * 32 + ((j & 7) << 2));
    }
#pragma unroll
    for (int i = 0; i < 2; ++i) {
      int j = tid + 256 * i;
      pb[i] = *(const u16x8*)(BT + (size_t)(n0 + (j >> 2)) * 256 + kt * 32 + ((j & 3) << 3));
    }
  };
  auto storestep = [&](int buf) {
#pragma unroll
    for (int i = 0; i < 4; ++i) {
      int j = tid + 256 * i;
      int row = j >> 3;
      int c16 = (j & 7) >> 1, half = j & 1;
      int swc = (c16 + ((row >> 1) & 3)) & 3;
      u16x4 u;
      u.x = f2bf(pa[i].x); u.y = f2bf(pa[i].y); u.z = f2bf(pa[i].z); u.w = f2bf(pa[i].w);
      *(u16x4*)&As[buf][row * 32 + swc * 8 + half * 4] = u;
    }
#pragma unroll
    for (int i = 0; i < 2; ++i) {
      int j = tid + 256 * i;
      int row = j >> 2;
      int swc = ((j & 3) + ((row >> 1) & 3)) & 3;
      *(u16x8*)&Bs[buf][row * 32 + swc * 8] = pb[i];
    }
  };

  loadstep(0);
  storestep(0);

#pragma unroll
  for (int kt = 0; kt < 8; ++kt) {
    if (kt < 7) loadstep(kt + 1);
    __builtin_amdgcn_sched_barrier(0);
    asm volatile("s_waitcnt lgkmcnt(0)" ::: "memory");
    __builtin_amdgcn_s_barrier();
    __builtin_amdgcn_sched_barrier(0);
    const int cur = kt & 1;
    bf16x8 a[4], b[4];
#pragma unroll
    for (int mi = 0; mi < 4; ++mi) {
      int rA = wr * 64 + mi * 16 + fr;
      int swc = (hi + ((rA >> 1) & 3)) & 3;
      a[mi] = *(const bf16x8*)&As[cur][rA * 32 + swc * 8];
    }
#pragma unroll
    for (int ni = 0; ni < 4; ++ni) {
      int rB = wc * 64 + ni * 16 + fr;
      int swc = (hi + ((rB >> 1) & 3)) & 3;
      b[ni] = *(const bf16x8*)&Bs[cur][rB * 32 + swc * 8];
    }
#pragma unroll
    for (int mi = 0; mi < 4; ++mi)
#pragma unroll
      for (int ni = 0; ni < 4; ++ni)
        acc[mi][ni] = __builtin_amdgcn_mfma_f32_16x16x32_bf16(
            b[ni], a[mi], acc[mi][ni], 0, 0, 0);
    if (kt < 7) storestep((kt + 1) & 1);
  }

#pragma unroll
  for (int mi = 0; mi < 4; ++mi) {
    int row = m0 + wr * 64 + mi * 16 + fr;
#pragma unroll
    for (int ni = 0; ni < 4; ++ni) {
      int col = n0 + wc * 64 + ni * 16 + hi * 4;
      float4 bv = *(const float4*)&bias[col];
      f32x4 v = acc[mi][ni];
      float4 o;
      o.x = v[0] + bv.x; o.y = v[1] + bv.y; o.z = v[2] + bv.z; o.w = v[3] + bv.w;
      *(float4*)&C[(size_t)row * Nn + col] = o;
    }
  }
}

// ---------------------------------------------------------------------------
// CSR build
// ---------------------------------------------------------------------------
__global__ __launch_bounds__(256) void hist_k(const int* __restrict__ src, int* __restrict__ deg)
{
  int e = blockIdx.x * 256 + threadIdx.x;
  if (e < N_EDGES) atomicAdd(&deg[src[e]], 1);
}

__global__ __launch_bounds__(1024) void scan_k(const int* __restrict__ deg,
                                               int* __restrict__ rowstart,
                                               int* __restrict__ cursor)
{
  __shared__ int s[1024];
  int tid = threadIdx.x;
  int4 v = ((const int4*)deg)[tid];
  int sum = v.x + v.y + v.z + v.w;
  s[tid] = sum;
  __syncthreads();
  for (int off = 1; off < 1024; off <<= 1) {
    int t = (tid >= off) ? s[tid - off] : 0;
    __syncthreads();
    s[tid] += t;
    __syncthreads();
  }
  int excl = s[tid] - sum;
  int r0 = excl, r1 = excl + v.x, r2 = r1 + v.y, r3 = r2 + v.z;
  rowstart[4 * tid + 0] = r0; cursor[4 * tid + 0] = r0;
  rowstart[4 * tid + 1] = r1; cursor[4 * tid + 1] = r1;
  rowstart[4 * tid + 2] = r2; cursor[4 * tid + 2] = r2;
  rowstart[4 * tid + 3] = r3; cursor[4 * tid + 3] = r3;
  if (tid == 1023) rowstart[4096] = r3 + v.w;
}

__global__ __launch_bounds__(256) void scatter_k(const int* __restrict__ src,
                                                 int* __restrict__ cursor,
                                                 int* __restrict__ csr)
{
  int e = blockIdx.x * 256 + threadIdx.x;
  if (e < N_EDGES) {
    int p = atomicAdd(&cursor[src[e]], 1);
    csr[p] = e;
  }
}

// ---------------------------------------------------------------------------
// Fused per-node kernel, MLP-maximized logit phase: 1 block (256 thr) per
// node; 32 edges processed CONCURRENTLY (8-lane group per edge); within a
// group lane j owns head j fully in-lane (8 indep float4 Ef loads + 8 K
// loads, no cross-lane reduce, no serial edge chain). ~4096 independent
// loads in flight per block.
// ---------------------------------------------------------------------------
__global__ __launch_bounds__(256) void node_attn_k(
    const float* __restrict__ QKVI, const float* __restrict__ Ef,
    const int* __restrict__ rowstart, const int* __restrict__ csr,
    const int* __restrict__ tgt, float* __restrict__ agg)
{
  __shared__ int   s_eid[MAXDEG];
  __shared__ int   s_tgt[MAXDEG];
  __shared__ float s_sc[HEADS][MAXDEGP];   // scores, then weights in-place
  __shared__ unsigned char s_alive[MAXDEG];
  __shared__ float s_self[8];
  __shared__ float s_wself[8];

  const float scl = 0.17677669529663687f;
  int i = blockIdx.x;
  int base = rowstart[i];
  int deg = rowstart[i + 1] - base;
  if (deg > MAXDEG) deg = MAXDEG;
  int tid = threadIdx.x;
  int g = tid >> 3;        // edge-group 0..31
  int j = tid & 7;         // head owned by this lane
  int h = tid >> 5, d = tid & 31;   // softmax indexing

  for (int t = tid; t < deg; t += 256) {
    int e = csr[base + t];
    s_eid[t] = e;
    s_tgt[t] = tgt[e];
  }
  __syncthreads();

  // per-lane Q head-slice: lane j holds Q_i[32j..32j+32) (L1-broadcast)
  float4 q[8];
#pragma unroll
  for (int c = 0; c < 8; ++c)
    q[c] = *(const float4*)&QKVI[(size_t)i * 1024 + j * 32 + 4 * c];

  // self score (group 0): lane j computes head j entirely in-lane
  if (g == 0) {
    float s = 0.f;
#pragma unroll
    for (int c = 0; c < 8; ++c) {
      float4 k4 = *(const float4*)&QKVI[(size_t)i * 1024 + 256 + j * 32 + 4 * c];
      s += dot4(q[c], k4);
    }
    s_self[j] = s * scl;
  }

  // edge logits: 32 edges concurrently; lane j -> head j, all loads independent
  for (int t = g; t < deg; t += 32) {
    int e = s_eid[t], tt = s_tgt[t];
    const float* efp = Ef + (size_t)e * 256 + j * 32;
    const float* kp  = QKVI + (size_t)tt * 1024 + 256 + j * 32;
    float s = 0.f;
#pragma unroll
    for (int c = 0; c < 8; ++c) {
      float4 ef = *(const float4*)(efp + 4 * c);
      float4 k4 = *(const float4*)(kp + 4 * c);
      float4 qk;
      qk.x = q[c].x + k4.x; qk.y = q[c].y + k4.y;
      qk.z = q[c].z + k4.z; qk.w = q[c].w + k4.w;
      s += dot4(ef, qk) + dot4(q[c], k4);
    }
    s_sc[j][t] = s * scl;
  }

  // dedup (keep max eid per tgt), drop self-target
  for (int t = tid; t < deg; t += 256) {
    int tt = s_tgt[t], ee = s_eid[t];
    bool alive = (tt != i);
    if (alive)
      for (int u = 0; u < deg; ++u)
        if (s_tgt[u] == tt && s_eid[u] > ee) { alive = false; break; }
    s_alive[t] = alive ? 1 : 0;
  }
  __syncthreads();

  // softmax: 32 lanes per head, in-place weights
  {
    float m = s_self[h];
    for (int t = d; t < deg; t += 32)
      if (s_alive[t]) m = fmaxf(m, s_sc[h][t]);
#pragma unroll
    for (int off = 16; off > 0; off >>= 1) m = fmaxf(m, __shfl_xor(m, off, 32));
    float lsum = 0.f;
    for (int t = d; t < deg; t += 32) {
      float wv = s_alive[t] ? expf(s_sc[h][t] - m) : 0.f;
      s_sc[h][t] = wv;
      lsum += wv;
    }
#pragma unroll
    for (int off = 16; off > 0; off >>= 1) lsum += __shfl_xor(lsum, off, 32);
    float wself = expf(s_self[h] - m);
    float inv = 1.f / (lsum + wself);
    if (d == 0) s_wself[h] = wself * inv;
    for (int t = d; t < deg; t += 32) s_sc[h][t] *= inv;
  }
  __syncthreads();

  // aggregate V (cols 512..767 of QKVI); col = tid -> coalesced 1KB/iter
  int col = tid;
  float accv = s_wself[h] * QKVI[(size_t)i * 1024 + 512 + col];
  for (int t = 0; t < deg; ++t)
    if (s_alive[t])
      accv += s_sc[h][t] * QKVI[(size_t)s_tgt[t] * 1024 + 512 + col];
  agg[(size_t)i * 256 + col] = accv;
}

// ---------------------------------------------------------------------------
// LayerNorm(x_proj + preo)
// ---------------------------------------------------------------------------
__global__ __launch_bounds__(256) void ln_k(
    const float* __restrict__ QKVI, const float* __restrict__ preo,
    const float* __restrict__ g, const float* __restrict__ b,
    float* __restrict__ out)
{
  int i = blockIdx.x, c = threadIdx.x;
  float v = QKVI[(size_t)i * 1024 + 768 + c] + preo[(size_t)i * 256 + c];
  float s1 = v, s2 = v * v;
#pragma unroll
  for (int off = 32; off > 0; off >>= 1) {
    s1 += __shfl_xor(s1, off, 64);
    s2 += __shfl_xor(s2, off, 64);
  }
  __shared__ float r1[4], r2[4];
  int w = c >> 6;
  if ((c & 63) == 0) { r1[w] = s1; r2[w] = s2; }
  __syncthreads();
  s1 = r1[0] + r1[1] + r1[2] + r1[3];
  s2 = r2[0] + r2[1] + r2[2] + r2[3];
  float mu  = s1 * (1.0f / 256.0f);
  float var = s2 * (1.0f / 256.0f) - mu * mu;
  out[(size_t)i * 256 + c] = (v - mu) * rsqrtf(var + 1e-5f) * g[c] + b[c];
}

// ---------------------------------------------------------------------------
extern "C" void kernel_launch(void* const* d_in, const int* in_sizes, int n_in,
                              void* d_out, int out_size, void* d_ws, size_t ws_size,
                              hipStream_t stream) {
  (void)in_sizes; (void)n_in; (void)out_size; (void)ws_size;
  const float* x  = (const float*)d_in[0];
  const int*   ei = (const int*)d_in[1];
  const float* ea = (const float*)d_in[2];
  const float* Wq = (const float*)d_in[3];  const float* bq = (const float*)d_in[4];
  const float* Wk = (const float*)d_in[5];  const float* bk = (const float*)d_in[6];
  const float* Wv = (const float*)d_in[7];  const float* bv = (const float*)d_in[8];
  const float* We = (const float*)d_in[9];  const float* be = (const float*)d_in[10];
  const float* Wo = (const float*)d_in[11]; const float* bo = (const float*)d_in[12];
  const float* Wi = (const float*)d_in[13]; const float* bi = (const float*)d_in[14];
  const float* lng = (const float*)d_in[15]; const float* lnb = (const float*)d_in[16];

  const int* src = ei;
  const int* tgt = ei + N_EDGES;

  char* ws = (char*)d_ws;
  u16*   WcatT   = (u16*)(ws + 0);              //  512 KB
  u16*   WeT     = (u16*)(ws + 524288);         //  128 KB
  u16*   WoT     = (u16*)(ws + 655360);         //  128 KB
  float* bcat    = (float*)(ws + 786432);       //    4 KB
  float* QKVI    = (float*)(ws + 790528);       //   16 MB
  int*   deg     = (int*)(ws + 17567744);       //   16 KB
  int*   rowstart= (int*)(ws + 17584128);       //   16.25 KB
  int*   cursor  = (int*)(ws + 17600768);       //   16 KB
  int*   csr     = (int*)(ws + 17617152);       //  512 KB
  float* agg     = (float*)(ws + 18141440);     //    4 MB
  float* preo    = (float*)(ws + 22335744);     //    4 MB

  float* outN = (float*)d_out;
  float* outE = (float*)d_out + (size_t)N_NODES * DIM;

  (void)hipMemsetAsync(deg, 0, N_NODES * sizeof(int), stream);

  prep_w_k<<<1536, 256, 0, stream>>>(Wq, Wk, Wv, Wi, We, Wo, bq, bk, bv, bi,
                                     WcatT, WeT, WoT, bcat);

  hist_k<<<N_EDGES / 256, 256, 0, stream>>>(src, deg);
  scan_k<<<1, 1024, 0, stream>>>(deg, rowstart, cursor);
  scatter_k<<<N_EDGES / 256, 256, 0, stream>>>(src, cursor, csr);

  // QKVI = x @ [Wq|Wk|Wv|Wi] + bcat
  gemm3_k<<<dim3(8, 32), 256, 0, stream>>>(x, WcatT, bcat, QKVI, 1024);

  // edge_out = edge_attr @ We + be
  gemm3_k<<<dim3(2, 1024), 256, 0, stream>>>(ea, WeT, be, outE, 256);

  // fused logits + softmax + V aggregation (block per node, 32 edges in flight)
  node_attn_k<<<N_NODES, 256, 0, stream>>>(QKVI, outE, rowstart, csr, tgt, agg);

  // preo = agg @ Wo + bo
  gemm3_k<<<dim3(2, 32), 256, 0, stream>>>(agg, WoT, bo, preo, 256);

  ln_k<<<N_NODES, 256, 0, stream>>>(QKVI, preo, lng, lnb, outN);
}

// Round 13
// 199.491 us; speedup vs baseline: 1.4680x; 1.4680x over previous
//
#include <hip/hip_runtime.h>

#define N_NODES 4096
#define N_EDGES 131072
#define DIM     256
#define HEADS   8
#define HDIM    32
#define MAXDEG  320
#define MAXDEGP 321   // (321h+t)%32 = (h+t)%32 -> 8 heads hit distinct banks

typedef unsigned short u16;
typedef unsigned int   u32;

using f32x4  = __attribute__((ext_vector_type(4))) float;
using bf16x8 = __attribute__((ext_vector_type(8))) short;
using u16x4  = __attribute__((ext_vector_type(4))) unsigned short;
using u16x8  = __attribute__((ext_vector_type(8))) unsigned short;

__device__ __forceinline__ u16 f2bf(float f) {
  u32 u = __float_as_uint(f);
  u += 0x7fffu + ((u >> 16) & 1u);   // RNE
  return (u16)(u >> 16);
}

__device__ __forceinline__ float dot4(float4 a, float4 b) {
  return a.x * b.x + a.y * b.y + a.z * b.z + a.w * b.w;
}

// ---------------------------------------------------------------------------
// Weight prep
// ---------------------------------------------------------------------------
__global__ __launch_bounds__(256) void prep_w_k(
    const float* __restrict__ Wq, const float* __restrict__ Wk,
    const float* __restrict__ Wv, const float* __restrict__ Wi,
    const float* __restrict__ We, const float* __restrict__ Wo,
    const float* __restrict__ bq, const float* __restrict__ bk,
    const float* __restrict__ bv, const float* __restrict__ bi,
    u16* __restrict__ WcatT, u16* __restrict__ WeT, u16* __restrict__ WoT,
    float* __restrict__ bcat)
{
  int n = blockIdx.x;
  int k = threadIdx.x;
  if (n < 1024) {
    const float* W = (n < 256) ? Wq : (n < 512) ? Wk : (n < 768) ? Wv : Wi;
    int nn = n & 255;
    WcatT[(size_t)n * 256 + k] = f2bf(W[(size_t)k * 256 + nn]);
    if (k == 0) {
      const float* b = (n < 256) ? bq : (n < 512) ? bk : (n < 768) ? bv : bi;
      bcat[n] = b[nn];
    }
  } else if (n < 1280) {
    int nn = n - 1024;
    WeT[(size_t)nn * 256 + k] = f2bf(We[(size_t)k * 256 + nn]);
  } else {
    int nn = n - 1280;
    WoT[(size_t)nn * 256 + k] = f2bf(Wo[(size_t)k * 256 + nn]);
  }
}

// ---------------------------------------------------------------------------
// 128x128 GEMM (proven 88us structure): C = A(fp32) @ B + bias, BT = B^T bf16.
// ---------------------------------------------------------------------------
__global__ __launch_bounds__(256) void gemm3_k(
    const float* __restrict__ Afp, const u16* __restrict__ BT,
    const float* __restrict__ bias, float* __restrict__ C, int Nn)
{
  __shared__ u16 As[2][128 * 32];
  __shared__ u16 Bs[2][128 * 32];
  const int n0 = blockIdx.x * 128;
  const int m0 = blockIdx.y * 128;
  const int tid = threadIdx.x;
  const int w = tid >> 6, l = tid & 63;
  const int wr = w >> 1, wc = w & 1;
  const int fr = l & 15, hi = l >> 4;

  float4 pa[4];
  u16x8  pb[2];
  f32x4  acc[4][4] = {};

  auto loadstep = [&](int kt) {
#pragma unroll
    for (int i = 0; i < 4; ++i) {
      int j = tid + 256 * i;
      pa[i] = *(const float4*)(Afp + (size_t)(m0 + (j >> 3)) * 256 + kt * 32 + ((j & 7) << 2));
    }
#pragma unroll
    for (int i = 0; i < 2; ++i) {
      int j = tid + 256 * i;
      pb[i] = *(const u16x8*)(BT + (size_t)(n0 + (j >> 2)) * 256 + kt * 32 + ((j & 3) << 3));
    }
  };
  auto storestep = [&](int buf) {
#pragma unroll
    for (int i = 0; i < 4; ++i) {
      int j = tid + 256 * i;
      int row = j >> 3;
      int c16 = (j & 7) >> 1, half = j & 1;
      int swc = (c16 + ((row >> 1) & 3)) & 3;
      u16x4 u;
      u.x = f2bf(pa[i].x); u.y = f2bf(pa[i].y); u.z = f2bf(pa[i].z); u.w = f2bf(pa[i].w);
      *(u16x4*)&As[buf][row * 32 + swc * 8 + half * 4] = u;
    }
#pragma unroll
    for (int i = 0; i < 2; ++i) {
      int j = tid + 256 * i;
      int row = j >> 2;
      int swc = ((j & 3) + ((row >> 1) & 3)) & 3;
      *(u16x8*)&Bs[buf][row * 32 + swc * 8] = pb[i];
    }
  };

  loadstep(0);
  storestep(0);

#pragma unroll
  for (int kt = 0; kt < 8; ++kt) {
    if (kt < 7) loadstep(kt + 1);
    __builtin_amdgcn_sched_barrier(0);
    asm volatile("s_waitcnt lgkmcnt(0)" ::: "memory");
    __builtin_amdgcn_s_barrier();
    __builtin_amdgcn_sched_barrier(0);
    const int cur = kt & 1;
    bf16x8 a[4], b[4];
#pragma unroll
    for (int mi = 0; mi < 4; ++mi) {
      int rA = wr * 64 + mi * 16 + fr;
      int swc = (hi + ((rA >> 1) & 3)) & 3;
      a[mi] = *(const bf16x8*)&As[cur][rA * 32 + swc * 8];
    }
#pragma unroll
    for (int ni = 0; ni < 4; ++ni) {
      int rB = wc * 64 + ni * 16 + fr;
      int swc = (hi + ((rB >> 1) & 3)) & 3;
      b[ni] = *(const bf16x8*)&Bs[cur][rB * 32 + swc * 8];
    }
#pragma unroll
    for (int mi = 0; mi < 4; ++mi)
#pragma unroll
      for (int ni = 0; ni < 4; ++ni)
        acc[mi][ni] = __builtin_amdgcn_mfma_f32_16x16x32_bf16(
            b[ni], a[mi], acc[mi][ni], 0, 0, 0);
    if (kt < 7) storestep((kt + 1) & 1);
  }

#pragma unroll
  for (int mi = 0; mi < 4; ++mi) {
    int row = m0 + wr * 64 + mi * 16 + fr;
#pragma unroll
    for (int ni = 0; ni < 4; ++ni) {
      int col = n0 + wc * 64 + ni * 16 + hi * 4;
      float4 bv = *(const float4*)&bias[col];
      f32x4 v = acc[mi][ni];
      float4 o;
      o.x = v[0] + bv.x; o.y = v[1] + bv.y; o.z = v[2] + bv.z; o.w = v[3] + bv.w;
      *(float4*)&C[(size_t)row * Nn + col] = o;
    }
  }
}

// ---------------------------------------------------------------------------
// CSR build
// ---------------------------------------------------------------------------
__global__ __launch_bounds__(256) void hist_k(const int* __restrict__ src, int* __restrict__ deg)
{
  int e = blockIdx.x * 256 + threadIdx.x;
  if (e < N_EDGES) atomicAdd(&deg[src[e]], 1);
}

__global__ __launch_bounds__(1024) void scan_k(const int* __restrict__ deg,
                                               int* __restrict__ rowstart,
                                               int* __restrict__ cursor)
{
  __shared__ int s[1024];
  int tid = threadIdx.x;
  int4 v = ((const int4*)deg)[tid];
  int sum = v.x + v.y + v.z + v.w;
  s[tid] = sum;
  __syncthreads();
  for (int off = 1; off < 1024; off <<= 1) {
    int t = (tid >= off) ? s[tid - off] : 0;
    __syncthreads();
    s[tid] += t;
    __syncthreads();
  }
  int excl = s[tid] - sum;
  int r0 = excl, r1 = excl + v.x, r2 = r1 + v.y, r3 = r2 + v.z;
  rowstart[4 * tid + 0] = r0; cursor[4 * tid + 0] = r0;
  rowstart[4 * tid + 1] = r1; cursor[4 * tid + 1] = r1;
  rowstart[4 * tid + 2] = r2; cursor[4 * tid + 2] = r2;
  rowstart[4 * tid + 3] = r3; cursor[4 * tid + 3] = r3;
  if (tid == 1023) rowstart[4096] = r3 + v.w;
}

__global__ __launch_bounds__(256) void scatter_k(const int* __restrict__ src,
                                                 int* __restrict__ cursor,
                                                 int* __restrict__ csr)
{
  int e = blockIdx.x * 256 + threadIdx.x;
  if (e < N_EDGES) {
    int p = atomicAdd(&cursor[src[e]], 1);
    csr[p] = e;
  }
}

// ---------------------------------------------------------------------------
// Fused per-node kernel (round-4 coalesced layout + explicit 4-deep MLP):
// 1 block per node, 4 waves. Logits: wave per edge (lane l reads floats
// 4l..4l+3 of the 1KB row -> perfectly coalesced), 4 edges batched per wave
// iteration (8 independent float4 loads in flight). Softmax: 32 lanes/head.
// Aggregate: branch-free (dead edges have weight 0), 4-deep unrolled.
// ---------------------------------------------------------------------------
__global__ __launch_bounds__(256) void node_attn_k(
    const float* __restrict__ QKVI, const float* __restrict__ Ef,
    const int* __restrict__ rowstart, const int* __restrict__ csr,
    const int* __restrict__ tgt, float* __restrict__ agg)
{
  __shared__ int   s_eid[MAXDEG];
  __shared__ int   s_tgt[MAXDEG];
  __shared__ float s_sc[HEADS][MAXDEGP];   // scores, then weights in-place
  __shared__ unsigned char s_alive[MAXDEG];
  __shared__ float s_self[8];
  __shared__ float s_wself[8];

  const float scl = 0.17677669529663687f;
  int i = blockIdx.x;
  int base = rowstart[i];
  int deg = rowstart[i + 1] - base;
  if (deg > MAXDEG) deg = MAXDEG;
  int tid = threadIdx.x;
  int w = tid >> 6, l = tid & 63;
  int h = tid >> 5, d = tid & 31;

  for (int t = tid; t < deg; t += 256) {
    int e = csr[base + t];
    s_eid[t] = e;
    s_tgt[t] = tgt[e];
  }
  __syncthreads();

  // Q_i: lane l holds dims 4l..4l+3 (head = l>>3)
  float4 q4 = *(const float4*)&QKVI[(size_t)i * 1024 + 4 * l];

  // self score (wave 0)
  if (w == 0) {
    float4 k4 = *(const float4*)&QKVI[(size_t)i * 1024 + 256 + 4 * l];
    float c = dot4(q4, k4);
    c += __shfl_xor(c, 1); c += __shfl_xor(c, 2); c += __shfl_xor(c, 4);
    if ((l & 7) == 0) s_self[l >> 3] = c * scl;
  }

  // edge logits: 4 edges per wave iteration, loads batched for MLP
  for (int t0 = w; t0 < deg; t0 += 16) {
    float4 ef[4], k4[4];
#pragma unroll
    for (int u = 0; u < 4; ++u) {
      int t = t0 + 4 * u;
      if (t < deg) {
        ef[u] = *(const float4*)&Ef[(size_t)s_eid[t] * 256 + 4 * l];
        k4[u] = *(const float4*)&QKVI[(size_t)s_tgt[t] * 1024 + 256 + 4 * l];
      }
    }
#pragma unroll
    for (int u = 0; u < 4; ++u) {
      int t = t0 + 4 * u;
      if (t < deg) {
        float c = dot4(q4, ef[u]) + dot4(ef[u], k4[u]) + dot4(q4, k4[u]);
        c += __shfl_xor(c, 1); c += __shfl_xor(c, 2); c += __shfl_xor(c, 4);
        if ((l & 7) == 0) s_sc[l >> 3][t] = c * scl;
      }
    }
  }

  // dedup (keep max eid per tgt), drop self-target
  for (int t = tid; t < deg; t += 256) {
    int tt = s_tgt[t], ee = s_eid[t];
    bool alive = (tt != i);
    if (alive)
      for (int u = 0; u < deg; ++u)
        if (s_tgt[u] == tt && s_eid[u] > ee) { alive = false; break; }
    s_alive[t] = alive ? 1 : 0;
  }
  __syncthreads();

  // softmax: 32 lanes per head; dead edges get weight exactly 0
  {
    float m = s_self[h];
    for (int t = d; t < deg; t += 32)
      if (s_alive[t]) m = fmaxf(m, s_sc[h][t]);
#pragma unroll
    for (int off = 16; off > 0; off >>= 1) m = fmaxf(m, __shfl_xor(m, off, 32));
    float lsum = 0.f;
    for (int t = d; t < deg; t += 32) {
      float wv = s_alive[t] ? expf(s_sc[h][t] - m) : 0.f;
      s_sc[h][t] = wv;
      lsum += wv;
    }
#pragma unroll
    for (int off = 16; off > 0; off >>= 1) lsum += __shfl_xor(lsum, off, 32);
    float wself = expf(s_self[h] - m);
    float inv = 1.f / (lsum + wself);
    if (d == 0) s_wself[h] = wself * inv;
    for (int t = d; t < deg; t += 32) s_sc[h][t] *= inv;
  }
  __syncthreads();

  // aggregate V: branch-free, 4-deep unrolled; col = tid -> coalesced
  int col = tid;
  float accv = s_wself[h] * QKVI[(size_t)i * 1024 + 512 + col];
  int t0 = 0;
  for (; t0 + 4 <= deg; t0 += 4) {
    float vl[4];
#pragma unroll
    for (int u = 0; u < 4; ++u)
      vl[u] = QKVI[(size_t)s_tgt[t0 + u] * 1024 + 512 + col];
#pragma unroll
    for (int u = 0; u < 4; ++u)
      accv += s_sc[h][t0 + u] * vl[u];
  }
  for (; t0 < deg; ++t0)
    accv += s_sc[h][t0] * QKVI[(size_t)s_tgt[t0] * 1024 + 512 + col];
  agg[(size_t)i * 256 + col] = accv;
}

// ---------------------------------------------------------------------------
// LayerNorm(x_proj + preo)
// ---------------------------------------------------------------------------
__global__ __launch_bounds__(256) void ln_k(
    const float* __restrict__ QKVI, const float* __restrict__ preo,
    const float* __restrict__ g, const float* __restrict__ b,
    float* __restrict__ out)
{
  int i = blockIdx.x, c = threadIdx.x;
  float v = QKVI[(size_t)i * 1024 + 768 + c] + preo[(size_t)i * 256 + c];
  float s1 = v, s2 = v * v;
#pragma unroll
  for (int off = 32; off > 0; off >>= 1) {
    s1 += __shfl_xor(s1, off, 64);
    s2 += __shfl_xor(s2, off, 64);
  }
  __shared__ float r1[4], r2[4];
  int w = c >> 6;
  if ((c & 63) == 0) { r1[w] = s1; r2[w] = s2; }
  __syncthreads();
  s1 = r1[0] + r1[1] + r1[2] + r1[3];
  s2 = r2[0] + r2[1] + r2[2] + r2[3];
  float mu  = s1 * (1.0f / 256.0f);
  float var = s2 * (1.0f / 256.0f) - mu * mu;
  out[(size_t)i * 256 + c] = (v - mu) * rsqrtf(var + 1e-5f) * g[c] + b[c];
}

// ---------------------------------------------------------------------------
extern "C" void kernel_launch(void* const* d_in, const int* in_sizes, int n_in,
                              void* d_out, int out_size, void* d_ws, size_t ws_size,
                              hipStream_t stream) {
  (void)in_sizes; (void)n_in; (void)out_size; (void)ws_size;
  const float* x  = (const float*)d_in[0];
  const int*   ei = (const int*)d_in[1];
  const float* ea = (const float*)d_in[2];
  const float* Wq = (const float*)d_in[3];  const float* bq = (const float*)d_in[4];
  const float* Wk = (const float*)d_in[5];  const float* bk = (const float*)d_in[6];
  const float* Wv = (const float*)d_in[7];  const float* bv = (const float*)d_in[8];
  const float* We = (const float*)d_in[9];  const float* be = (const float*)d_in[10];
  const float* Wo = (const float*)d_in[11]; const float* bo = (const float*)d_in[12];
  const float* Wi = (const float*)d_in[13]; const float* bi = (const float*)d_in[14];
  const float* lng = (const float*)d_in[15]; const float* lnb = (const float*)d_in[16];

  const int* src = ei;
  const int* tgt = ei + N_EDGES;

  char* ws = (char*)d_ws;
  u16*   WcatT   = (u16*)(ws + 0);              //  512 KB
  u16*   WeT     = (u16*)(ws + 524288);         //  128 KB
  u16*   WoT     = (u16*)(ws + 655360);         //  128 KB
  float* bcat    = (float*)(ws + 786432);       //    4 KB
  float* QKVI    = (float*)(ws + 790528);       //   16 MB
  int*   deg     = (int*)(ws + 17567744);       //   16 KB
  int*   rowstart= (int*)(ws + 17584128);       //   16.25 KB
  int*   cursor  = (int*)(ws + 17600768);       //   16 KB
  int*   csr     = (int*)(ws + 17617152);       //  512 KB
  float* agg     = (float*)(ws + 18141440);     //    4 MB
  float* preo    = (float*)(ws + 22335744);     //    4 MB

  float* outN = (float*)d_out;
  float* outE = (float*)d_out + (size_t)N_NODES * DIM;

  (void)hipMemsetAsync(deg, 0, N_NODES * sizeof(int), stream);

  prep_w_k<<<1536, 256, 0, stream>>>(Wq, Wk, Wv, Wi, We, Wo, bq, bk, bv, bi,
                                     WcatT, WeT, WoT, bcat);

  hist_k<<<N_EDGES / 256, 256, 0, stream>>>(src, deg);
  scan_k<<<1, 1024, 0, stream>>>(deg, rowstart, cursor);
  scatter_k<<<N_EDGES / 256, 256, 0, stream>>>(src, cursor, csr);

  // QKVI = x @ [Wq|Wk|Wv|Wi] + bcat
  gemm3_k<<<dim3(8, 32), 256, 0, stream>>>(x, WcatT, bcat, QKVI, 1024);

  // edge_out = edge_attr @ We + be
  gemm3_k<<<dim3(2, 1024), 256, 0, stream>>>(ea, WeT, be, outE, 256);

  // fused logits + softmax + V aggregation
  node_attn_k<<<N_NODES, 256, 0, stream>>>(QKVI, outE, rowstart, csr, tgt, agg);

  // preo = agg @ Wo + bo
  gemm3_k<<<dim3(2, 32), 256, 0, stream>>>(agg, WoT, bo, preo, 256);

  ln_k<<<N_NODES, 256, 0, stream>>>(QKVI, preo, lng, lnb, outN);
}

// Round 14
// 198.470 us; speedup vs baseline: 1.4756x; 1.0051x over previous
//
#include <hip/hip_runtime.h>

#define N_NODES 4096
#define N_EDGES 131072
#define DIM     256
#define HEADS   8
#define HDIM    32
#define MAXDEG  320
#define MAXDEGP 321   // (321h+t)%32 = (h+t)%32 -> 8 heads hit distinct banks

typedef unsigned short u16;
typedef unsigned int   u32;

using f32x4  = __attribute__((ext_vector_type(4))) float;
using bf16x8 = __attribute__((ext_vector_type(8))) short;
using u16x4  = __attribute__((ext_vector_type(4))) unsigned short;
using u16x8  = __attribute__((ext_vector_type(8))) unsigned short;

__device__ __forceinline__ u16 f2bf(float f) {
  u32 u = __float_as_uint(f);
  u += 0x7fffu + ((u >> 16) & 1u);   // RNE
  return (u16)(u >> 16);
}

__device__ __forceinline__ float dot4(float4 a, float4 b) {
  return a.x * b.x + a.y * b.y + a.z * b.z + a.w * b.w;
}

// ---------------------------------------------------------------------------
// Weight prep
// ---------------------------------------------------------------------------
__global__ __launch_bounds__(256) void prep_w_k(
    const float* __restrict__ Wq, const float* __restrict__ Wk,
    const float* __restrict__ Wv, const float* __restrict__ Wi,
    const float* __restrict__ We, const float* __restrict__ Wo,
    const float* __restrict__ bq, const float* __restrict__ bk,
    const float* __restrict__ bv, const float* __restrict__ bi,
    u16* __restrict__ WcatT, u16* __restrict__ WeT, u16* __restrict__ WoT,
    float* __restrict__ bcat)
{
  int n = blockIdx.x;
  int k = threadIdx.x;
  if (n < 1024) {
    const float* W = (n < 256) ? Wq : (n < 512) ? Wk : (n < 768) ? Wv : Wi;
    int nn = n & 255;
    WcatT[(size_t)n * 256 + k] = f2bf(W[(size_t)k * 256 + nn]);
    if (k == 0) {
      const float* b = (n < 256) ? bq : (n < 512) ? bk : (n < 768) ? bv : bi;
      bcat[n] = b[nn];
    }
  } else if (n < 1280) {
    int nn = n - 1024;
    WeT[(size_t)nn * 256 + k] = f2bf(We[(size_t)k * 256 + nn]);
  } else {
    int nn = n - 1280;
    WoT[(size_t)nn * 256 + k] = f2bf(Wo[(size_t)k * 256 + nn]);
  }
}

// ---------------------------------------------------------------------------
// 128x128 GEMM (proven 88us structure): C = A(fp32) @ B + bias, BT = B^T bf16.
// ---------------------------------------------------------------------------
__global__ __launch_bounds__(256) void gemm3_k(
    const float* __restrict__ Afp, const u16* __restrict__ BT,
    const float* __restrict__ bias, float* __restrict__ C, int Nn)
{
  __shared__ u16 As[2][128 * 32];
  __shared__ u16 Bs[2][128 * 32];
  const int n0 = blockIdx.x * 128;
  const int m0 = blockIdx.y * 128;
  const int tid = threadIdx.x;
  const int w = tid >> 6, l = tid & 63;
  const int wr = w >> 1, wc = w & 1;
  const int fr = l & 15, hi = l >> 4;

  float4 pa[4];
  u16x8  pb[2];
  f32x4  acc[4][4] = {};

  auto loadstep = [&](int kt) {
#pragma unroll
    for (int i = 0; i < 4; ++i) {
      int j = tid + 256 * i;
      pa[i] = *(const float4*)(Afp + (size_t)(m0 + (j >> 3)) * 256 + kt * 32 + ((j & 7) << 2));
    }
#pragma unroll
    for (int i = 0; i < 2; ++i) {
      int j = tid + 256 * i;
      pb[i] = *(const u16x8*)(BT + (size_t)(n0 + (j >> 2)) * 256 + kt * 32 + ((j & 3) << 3));
    }
  };
  auto storestep = [&](int buf) {
#pragma unroll
    for (int i = 0; i < 4; ++i) {
      int j = tid + 256 * i;
      int row = j >> 3;
      int c16 = (j & 7) >> 1, half = j & 1;
      int swc = (c16 + ((row >> 1) & 3)) & 3;
      u16x4 u;
      u.x = f2bf(pa[i].x); u.y = f2bf(pa[i].y); u.z = f2bf(pa[i].z); u.w = f2bf(pa[i].w);
      *(u16x4*)&As[buf][row * 32 + swc * 8 + half * 4] = u;
    }
#pragma unroll
    for (int i = 0; i < 2; ++i) {
      int j = tid + 256 * i;
      int row = j >> 2;
      int swc = ((j & 3) + ((row >> 1) & 3)) & 3;
      *(u16x8*)&Bs[buf][row * 32 + swc * 8] = pb[i];
    }
  };

  loadstep(0);
  storestep(0);

#pragma unroll
  for (int kt = 0; kt < 8; ++kt) {
    if (kt < 7) loadstep(kt + 1);
    __builtin_amdgcn_sched_barrier(0);
    asm volatile("s_waitcnt lgkmcnt(0)" ::: "memory");
    __builtin_amdgcn_s_barrier();
    __builtin_amdgcn_sched_barrier(0);
    const int cur = kt & 1;
    bf16x8 a[4], b[4];
#pragma unroll
    for (int mi = 0; mi < 4; ++mi) {
      int rA = wr * 64 + mi * 16 + fr;
      int swc = (hi + ((rA >> 1) & 3)) & 3;
      a[mi] = *(const bf16x8*)&As[cur][rA * 32 + swc * 8];
    }
#pragma unroll
    for (int ni = 0; ni < 4; ++ni) {
      int rB = wc * 64 + ni * 16 + fr;
      int swc = (hi + ((rB >> 1) & 3)) & 3;
      b[ni] = *(const bf16x8*)&Bs[cur][rB * 32 + swc * 8];
    }
#pragma unroll
    for (int mi = 0; mi < 4; ++mi)
#pragma unroll
      for (int ni = 0; ni < 4; ++ni)
        acc[mi][ni] = __builtin_amdgcn_mfma_f32_16x16x32_bf16(
            b[ni], a[mi], acc[mi][ni], 0, 0, 0);
    if (kt < 7) storestep((kt + 1) & 1);
  }

#pragma unroll
  for (int mi = 0; mi < 4; ++mi) {
    int row = m0 + wr * 64 + mi * 16 + fr;
#pragma unroll
    for (int ni = 0; ni < 4; ++ni) {
      int col = n0 + wc * 64 + ni * 16 + hi * 4;
      float4 bv = *(const float4*)&bias[col];
      f32x4 v = acc[mi][ni];
      float4 o;
      o.x = v[0] + bv.x; o.y = v[1] + bv.y; o.z = v[2] + bv.z; o.w = v[3] + bv.w;
      *(float4*)&C[(size_t)row * Nn + col] = o;
    }
  }
}

// ---------------------------------------------------------------------------
// CSR build
// ---------------------------------------------------------------------------
__global__ __launch_bounds__(256) void hist_k(const int* __restrict__ src, int* __restrict__ deg)
{
  int e = blockIdx.x * 256 + threadIdx.x;
  if (e < N_EDGES) atomicAdd(&deg[src[e]], 1);
}

__global__ __launch_bounds__(1024) void scan_k(const int* __restrict__ deg,
                                               int* __restrict__ rowstart,
                                               int* __restrict__ cursor)
{
  __shared__ int s[1024];
  int tid = threadIdx.x;
  int4 v = ((const int4*)deg)[tid];
  int sum = v.x + v.y + v.z + v.w;
  s[tid] = sum;
  __syncthreads();
  for (int off = 1; off < 1024; off <<= 1) {
    int t = (tid >= off) ? s[tid - off] : 0;
    __syncthreads();
    s[tid] += t;
    __syncthreads();
  }
  int excl = s[tid] - sum;
  int r0 = excl, r1 = excl + v.x, r2 = r1 + v.y, r3 = r2 + v.z;
  rowstart[4 * tid + 0] = r0; cursor[4 * tid + 0] = r0;
  rowstart[4 * tid + 1] = r1; cursor[4 * tid + 1] = r1;
  rowstart[4 * tid + 2] = r2; cursor[4 * tid + 2] = r2;
  rowstart[4 * tid + 3] = r3; cursor[4 * tid + 3] = r3;
  if (tid == 1023) rowstart[4096] = r3 + v.w;
}

__global__ __launch_bounds__(256) void scatter_k(const int* __restrict__ src,
                                                 int* __restrict__ cursor,
                                                 int* __restrict__ csr)
{
  int e = blockIdx.x * 256 + threadIdx.x;
  if (e < N_EDGES) {
    int p = atomicAdd(&cursor[src[e]], 1);
    csr[p] = e;
  }
}

// ---------------------------------------------------------------------------
// Fused per-node kernel (round-4 coalesced layout + explicit 4-deep MLP):
// 1 block per node, 4 waves. Logits: wave per edge (lane l reads floats
// 4l..4l+3 of the 1KB row -> perfectly coalesced), 4 edges batched per wave
// iteration (8 independent float4 loads in flight). Softmax: 32 lanes/head.
// Aggregate: branch-free (dead edges have weight 0), 4-deep unrolled.
// ---------------------------------------------------------------------------
__global__ __launch_bounds__(256) void node_attn_k(
    const float* __restrict__ QKVI, const float* __restrict__ Ef,
    const int* __restrict__ rowstart, const int* __restrict__ csr,
    const int* __restrict__ tgt, float* __restrict__ agg)
{
  __shared__ int   s_eid[MAXDEG];
  __shared__ int   s_tgt[MAXDEG];
  __shared__ float s_sc[HEADS][MAXDEGP];   // scores, then weights in-place
  __shared__ unsigned char s_alive[MAXDEG];
  __shared__ float s_self[8];
  __shared__ float s_wself[8];

  const float scl = 0.17677669529663687f;
  int i = blockIdx.x;
  int base = rowstart[i];
  int deg = rowstart[i + 1] - base;
  if (deg > MAXDEG) deg = MAXDEG;
  int tid = threadIdx.x;
  int w = tid >> 6, l = tid & 63;
  int h = tid >> 5, d = tid & 31;

  for (int t = tid; t < deg; t += 256) {
    int e = csr[base + t];
    s_eid[t] = e;
    s_tgt[t] = tgt[e];
  }
  __syncthreads();

  // Q_i: lane l holds dims 4l..4l+3 (head = l>>3)
  float4 q4 = *(const float4*)&QKVI[(size_t)i * 1024 + 4 * l];

  // self score (wave 0)
  if (w == 0) {
    float4 k4 = *(const float4*)&QKVI[(size_t)i * 1024 + 256 + 4 * l];
    float c = dot4(q4, k4);
    c += __shfl_xor(c, 1); c += __shfl_xor(c, 2); c += __shfl_xor(c, 4);
    if ((l & 7) == 0) s_self[l >> 3] = c * scl;
  }

  // edge logits: 4 edges per wave iteration, loads batched for MLP
  for (int t0 = w; t0 < deg; t0 += 16) {
    float4 ef[4], k4[4];
#pragma unroll
    for (int u = 0; u < 4; ++u) {
      int t = t0 + 4 * u;
      if (t < deg) {
        ef[u] = *(const float4*)&Ef[(size_t)s_eid[t] * 256 + 4 * l];
        k4[u] = *(const float4*)&QKVI[(size_t)s_tgt[t] * 1024 + 256 + 4 * l];
      }
    }
#pragma unroll
    for (int u = 0; u < 4; ++u) {
      int t = t0 + 4 * u;
      if (t < deg) {
        float c = dot4(q4, ef[u]) + dot4(ef[u], k4[u]) + dot4(q4, k4[u]);
        c += __shfl_xor(c, 1); c += __shfl_xor(c, 2); c += __shfl_xor(c, 4);
        if ((l & 7) == 0) s_sc[l >> 3][t] = c * scl;
      }
    }
  }

  // dedup (keep max eid per tgt), drop self-target
  for (int t = tid; t < deg; t += 256) {
    int tt = s_tgt[t], ee = s_eid[t];
    bool alive = (tt != i);
    if (alive)
      for (int u = 0; u < deg; ++u)
        if (s_tgt[u] == tt && s_eid[u] > ee) { alive = false; break; }
    s_alive[t] = alive ? 1 : 0;
  }
  __syncthreads();

  // softmax: 32 lanes per head; dead edges get weight exactly 0
  {
    float m = s_self[h];
    for (int t = d; t < deg; t += 32)
      if (s_alive[t]) m = fmaxf(m, s_sc[h][t]);
#pragma unroll
    for (int off = 16; off > 0; off >>= 1) m = fmaxf(m, __shfl_xor(m, off, 32));
    float lsum = 0.f;
    for (int t = d; t < deg; t += 32) {
      float wv = s_alive[t] ? expf(s_sc[h][t] - m) : 0.f;
      s_sc[h][t] = wv;
      lsum += wv;
    }
#pragma unroll
    for (int off = 16; off > 0; off >>= 1) lsum += __shfl_xor(lsum, off, 32);
    float wself = expf(s_self[h] - m);
    float inv = 1.f / (lsum + wself);
    if (d == 0) s_wself[h] = wself * inv;
    for (int t = d; t < deg; t += 32) s_sc[h][t] *= inv;
  }
  __syncthreads();

  // aggregate V: branch-free, 4-deep unrolled; col = tid -> coalesced
  int col = tid;
  float accv = s_wself[h] * QKVI[(size_t)i * 1024 + 512 + col];
  int t0 = 0;
  for (; t0 + 4 <= deg; t0 += 4) {
    float vl[4];
#pragma unroll
    for (int u = 0; u < 4; ++u)
      vl[u] = QKVI[(size_t)s_tgt[t0 + u] * 1024 + 512 + col];
#pragma unroll
    for (int u = 0; u < 4; ++u)
      accv += s_sc[h][t0 + u] * vl[u];
  }
  for (; t0 < deg; ++t0)
    accv += s_sc[h][t0] * QKVI[(size_t)s_tgt[t0] * 1024 + 512 + col];
  agg[(size_t)i * 256 + col] = accv;
}

// ---------------------------------------------------------------------------
// LayerNorm(x_proj + preo)
// ---------------------------------------------------------------------------
__global__ __launch_bounds__(256) void ln_k(
    const float* __restrict__ QKVI, const float* __restrict__ preo,
    const float* __restrict__ g, const float* __restrict__ b,
    float* __restrict__ out)
{
  int i = blockIdx.x, c = threadIdx.x;
  float v = QKVI[(size_t)i * 1024 + 768 + c] + preo[(size_t)i * 256 + c];
  float s1 = v, s2 = v * v;
#pragma unroll
  for (int off = 32; off > 0; off >>= 1) {
    s1 += __shfl_xor(s1, off, 64);
    s2 += __shfl_xor(s2, off, 64);
  }
  __shared__ float r1[4], r2[4];
  int w = c >> 6;
  if ((c & 63) == 0) { r1[w] = s1; r2[w] = s2; }
  __syncthreads();
  s1 = r1[0] + r1[1] + r1[2] + r1[3];
  s2 = r2[0] + r2[1] + r2[2] + r2[3];
  float mu  = s1 * (1.0f / 256.0f);
  float var = s2 * (1.0f / 256.0f) - mu * mu;
  out[(size_t)i * 256 + c] = (v - mu) * rsqrtf(var + 1e-5f) * g[c] + b[c];
}

// ---------------------------------------------------------------------------
extern "C" void kernel_launch(void* const* d_in, const int* in_sizes, int n_in,
                              void* d_out, int out_size, void* d_ws, size_t ws_size,
                              hipStream_t stream) {
  (void)in_sizes; (void)n_in; (void)out_size; (void)ws_size;
  const float* x  = (const float*)d_in[0];
  const int*   ei = (const int*)d_in[1];
  const float* ea = (const float*)d_in[2];
  const float* Wq = (const float*)d_in[3];  const float* bq = (const float*)d_in[4];
  const float* Wk = (const float*)d_in[5];  const float* bk = (const float*)d_in[6];
  const float* Wv = (const float*)d_in[7];  const float* bv = (const float*)d_in[8];
  const float* We = (const float*)d_in[9];  const float* be = (const float*)d_in[10];
  const float* Wo = (const float*)d_in[11]; const float* bo = (const float*)d_in[12];
  const float* Wi = (const float*)d_in[13]; const float* bi = (const float*)d_in[14];
  const float* lng = (const float*)d_in[15]; const float* lnb = (const float*)d_in[16];

  const int* src = ei;
  const int* tgt = ei + N_EDGES;

  char* ws = (char*)d_ws;
  u16*   WcatT   = (u16*)(ws + 0);              //  512 KB
  u16*   WeT     = (u16*)(ws + 524288);         //  128 KB
  u16*   WoT     = (u16*)(ws + 655360);         //  128 KB
  float* bcat    = (float*)(ws + 786432);       //    4 KB
  float* QKVI    = (float*)(ws + 790528);       //   16 MB
  int*   deg     = (int*)(ws + 17567744);       //   16 KB
  int*   rowstart= (int*)(ws + 17584128);       //   16.25 KB
  int*   cursor  = (int*)(ws + 17600768);       //   16 KB
  int*   csr     = (int*)(ws + 17617152);       //  512 KB
  float* agg     = (float*)(ws + 18141440);     //    4 MB
  float* preo    = (float*)(ws + 22335744);     //    4 MB

  float* outN = (float*)d_out;
  float* outE = (float*)d_out + (size_t)N_NODES * DIM;

  (void)hipMemsetAsync(deg, 0, N_NODES * sizeof(int), stream);

  prep_w_k<<<1536, 256, 0, stream>>>(Wq, Wk, Wv, Wi, We, Wo, bq, bk, bv, bi,
                                     WcatT, WeT, WoT, bcat);

  hist_k<<<N_EDGES / 256, 256, 0, stream>>>(src, deg);
  scan_k<<<1, 1024, 0, stream>>>(deg, rowstart, cursor);
  scatter_k<<<N_EDGES / 256, 256, 0, stream>>>(src, cursor, csr);

  // QKVI = x @ [Wq|Wk|Wv|Wi] + bcat
  gemm3_k<<<dim3(8, 32), 256, 0, stream>>>(x, WcatT, bcat, QKVI, 1024);

  // edge_out = edge_attr @ We + be
  gemm3_k<<<dim3(2, 1024), 256, 0, stream>>>(ea, WeT, be, outE, 256);

  // fused logits + softmax + V aggregation
  node_attn_k<<<N_NODES, 256, 0, stream>>>(QKVI, outE, rowstart, csr, tgt, agg);

  // preo = agg @ Wo + bo
  gemm3_k<<<dim3(2, 32), 256, 0, stream>>>(agg, WoT, bo, preo, 256);

  ln_k<<<N_NODES, 256, 0, stream>>>(QKVI, preo, lng, lnb, outN);
}

// Round 15
// 180.469 us; speedup vs baseline: 1.6228x; 1.0997x over previous
//
#include <hip/hip_runtime.h>

#define N_NODES 4096
#define N_EDGES 131072
#define DIM     256
#define HEADS   8
#define HDIM    32
#define MAXDEG  320
#define MAXDEGP 321   // (321h+t)%32 = (h+t)%32 -> 8 heads hit distinct banks

typedef unsigned short u16;
typedef unsigned int   u32;

using f32x4  = __attribute__((ext_vector_type(4))) float;
using bf16x8 = __attribute__((ext_vector_type(8))) short;
using u16x4  = __attribute__((ext_vector_type(4))) unsigned short;
using u16x8  = __attribute__((ext_vector_type(8))) unsigned short;

__device__ __forceinline__ u16 f2bf(float f) {
  u32 u = __float_as_uint(f);
  u += 0x7fffu + ((u >> 16) & 1u);   // RNE
  return (u16)(u >> 16);
}

__device__ __forceinline__ float dot4(float4 a, float4 b) {
  return a.x * b.x + a.y * b.y + a.z * b.z + a.w * b.w;
}

// ---------------------------------------------------------------------------
// Weight prep (+ deg zeroing folded in: blocks 1536..1551)
// ---------------------------------------------------------------------------
__global__ __launch_bounds__(256) void prep_w_k(
    const float* __restrict__ Wq, const float* __restrict__ Wk,
    const float* __restrict__ Wv, const float* __restrict__ Wi,
    const float* __restrict__ We, const float* __restrict__ Wo,
    const float* __restrict__ bq, const float* __restrict__ bk,
    const float* __restrict__ bv, const float* __restrict__ bi,
    u16* __restrict__ WcatT, u16* __restrict__ WeT, u16* __restrict__ WoT,
    float* __restrict__ bcat, int* __restrict__ deg)
{
  int n = blockIdx.x;
  int k = threadIdx.x;
  if (n < 1024) {
    const float* W = (n < 256) ? Wq : (n < 512) ? Wk : (n < 768) ? Wv : Wi;
    int nn = n & 255;
    WcatT[(size_t)n * 256 + k] = f2bf(W[(size_t)k * 256 + nn]);
    if (k == 0) {
      const float* b = (n < 256) ? bq : (n < 512) ? bk : (n < 768) ? bv : bi;
      bcat[n] = b[nn];
    }
  } else if (n < 1280) {
    int nn = n - 1024;
    WeT[(size_t)nn * 256 + k] = f2bf(We[(size_t)k * 256 + nn]);
  } else if (n < 1536) {
    int nn = n - 1280;
    WoT[(size_t)nn * 256 + k] = f2bf(Wo[(size_t)k * 256 + nn]);
  } else {
    deg[(n - 1536) * 256 + k] = 0;
  }
}

// ---------------------------------------------------------------------------
// 128x128 GEMM body (proven 88us structure): C = A(fp32) @ B + bias.
// BT = B^T bf16. LDS dbuf, reg prefetch, lgkmcnt-only barrier, XOR swizzle.
// Lane holds C[m=mi*16+fr][n=ni*16+hi*4+reg] via mfma(b,a,acc) swap.
// ---------------------------------------------------------------------------
__device__ __forceinline__ void gemm3_body(
    const float* __restrict__ Afp, const u16* __restrict__ BT,
    const float* __restrict__ bias, float* __restrict__ C, int Nn,
    int n0, int m0, u16 (&As)[2][128 * 32], u16 (&Bs)[2][128 * 32])
{
  const int tid = threadIdx.x;
  const int w = tid >> 6, l = tid & 63;
  const int wr = w >> 1, wc = w & 1;
  const int fr = l & 15, hi = l >> 4;

  float4 pa[4];
  u16x8  pb[2];
  f32x4  acc[4][4] = {};

  auto loadstep = [&](int kt) {
#pragma unroll
    for (int i = 0; i < 4; ++i) {
      int j = tid + 256 * i;
      pa[i] = *(const float4*)(Afp + (size_t)(m0 + (j >> 3)) * 256 + kt * 32 + ((j & 7) << 2));
    }
#pragma unroll
    for (int i = 0; i < 2; ++i) {
      int j = tid + 256 * i;
      pb[i] = *(const u16x8*)(BT + (size_t)(n0 + (j >> 2)) * 256 + kt * 32 + ((j & 3) << 3));
    }
  };
  auto storestep = [&](int buf) {
#pragma unroll
    for (int i = 0; i < 4; ++i) {
      int j = tid + 256 * i;
      int row = j >> 3;
      int c16 = (j & 7) >> 1, half = j & 1;
      int swc = (c16 + ((row >> 1) & 3)) & 3;
      u16x4 u;
      u.x = f2bf(pa[i].x); u.y = f2bf(pa[i].y); u.z = f2bf(pa[i].z); u.w = f2bf(pa[i].w);
      *(u16x4*)&As[buf][row * 32 + swc * 8 + half * 4] = u;
    }
#pragma unroll
    for (int i = 0; i < 2; ++i) {
      int j = tid + 256 * i;
      int row = j >> 2;
      int swc = ((j & 3) + ((row >> 1) & 3)) & 3;
      *(u16x8*)&Bs[buf][row * 32 + swc * 8] = pb[i];
    }
  };

  loadstep(0);
  storestep(0);

#pragma unroll
  for (int kt = 0; kt < 8; ++kt) {
    if (kt < 7) loadstep(kt + 1);
    __builtin_amdgcn_sched_barrier(0);
    asm volatile("s_waitcnt lgkmcnt(0)" ::: "memory");
    __builtin_amdgcn_s_barrier();
    __builtin_amdgcn_sched_barrier(0);
    const int cur = kt & 1;
    bf16x8 a[4], b[4];
#pragma unroll
    for (int mi = 0; mi < 4; ++mi) {
      int rA = wr * 64 + mi * 16 + fr;
      int swc = (hi + ((rA >> 1) & 3)) & 3;
      a[mi] = *(const bf16x8*)&As[cur][rA * 32 + swc * 8];
    }
#pragma unroll
    for (int ni = 0; ni < 4; ++ni) {
      int rB = wc * 64 + ni * 16 + fr;
      int swc = (hi + ((rB >> 1) & 3)) & 3;
      b[ni] = *(const bf16x8*)&Bs[cur][rB * 32 + swc * 8];
    }
#pragma unroll
    for (int mi = 0; mi < 4; ++mi)
#pragma unroll
      for (int ni = 0; ni < 4; ++ni)
        acc[mi][ni] = __builtin_amdgcn_mfma_f32_16x16x32_bf16(
            b[ni], a[mi], acc[mi][ni], 0, 0, 0);
    if (kt < 7) storestep((kt + 1) & 1);
  }

#pragma unroll
  for (int mi = 0; mi < 4; ++mi) {
    int row = m0 + wr * 64 + mi * 16 + fr;
#pragma unroll
    for (int ni = 0; ni < 4; ++ni) {
      int col = n0 + wc * 64 + ni * 16 + hi * 4;
      float4 bv = *(const float4*)&bias[col];
      f32x4 v = acc[mi][ni];
      float4 o;
      o.x = v[0] + bv.x; o.y = v[1] + bv.y; o.z = v[2] + bv.z; o.w = v[3] + bv.w;
      *(float4*)&C[(size_t)row * Nn + col] = o;
    }
  }
}

// Merged dispatch: 2304 blocks = 2048 edge-GEMM + 256 QKVI-GEMM, interleaved
// (every 9th block = QKVI) so MFMA-denser QKVI blocks co-reside with
// memory-stalled edge blocks on every CU.
__global__ __launch_bounds__(256) void gemm_all_k(
    const float* __restrict__ ea, const u16* __restrict__ WeT,
    const float* __restrict__ be, float* __restrict__ outE,
    const float* __restrict__ x, const u16* __restrict__ WcatT,
    const float* __restrict__ bcat, float* __restrict__ QKVI)
{
  __shared__ u16 As[2][128 * 32];
  __shared__ u16 Bs[2][128 * 32];
  int bid = blockIdx.x;
  int r = bid % 9, q = bid / 9;
  if (r < 8) {
    int j = q * 8 + r;                         // 0..2047
    gemm3_body(ea, WeT, be, outE, 256, (j & 1) * 128, (j >> 1) * 128, As, Bs);
  } else {
    gemm3_body(x, WcatT, bcat, QKVI, 1024, (q & 7) * 128, (q >> 3) * 128, As, Bs);
  }
}

// Standalone (Wo projection)
__global__ __launch_bounds__(256) void gemm3_k(
    const float* __restrict__ Afp, const u16* __restrict__ BT,
    const float* __restrict__ bias, float* __restrict__ C, int Nn)
{
  __shared__ u16 As[2][128 * 32];
  __shared__ u16 Bs[2][128 * 32];
  gemm3_body(Afp, BT, bias, C, Nn, blockIdx.x * 128, blockIdx.y * 128, As, Bs);
}

// ---------------------------------------------------------------------------
// CSR build
// ---------------------------------------------------------------------------
__global__ __launch_bounds__(256) void hist_k(const int* __restrict__ src, int* __restrict__ deg)
{
  int e = blockIdx.x * 256 + threadIdx.x;
  if (e < N_EDGES) atomicAdd(&deg[src[e]], 1);
}

__global__ __launch_bounds__(1024) void scan_k(const int* __restrict__ deg,
                                               int* __restrict__ rowstart,
                                               int* __restrict__ cursor)
{
  __shared__ int s[1024];
  int tid = threadIdx.x;
  int4 v = ((const int4*)deg)[tid];
  int sum = v.x + v.y + v.z + v.w;
  s[tid] = sum;
  __syncthreads();
  for (int off = 1; off < 1024; off <<= 1) {
    int t = (tid >= off) ? s[tid - off] : 0;
    __syncthreads();
    s[tid] += t;
    __syncthreads();
  }
  int excl = s[tid] - sum;
  int r0 = excl, r1 = excl + v.x, r2 = r1 + v.y, r3 = r2 + v.z;
  rowstart[4 * tid + 0] = r0; cursor[4 * tid + 0] = r0;
  rowstart[4 * tid + 1] = r1; cursor[4 * tid + 1] = r1;
  rowstart[4 * tid + 2] = r2; cursor[4 * tid + 2] = r2;
  rowstart[4 * tid + 3] = r3; cursor[4 * tid + 3] = r3;
  if (tid == 1023) rowstart[4096] = r3 + v.w;
}

__global__ __launch_bounds__(256) void scatter_k(const int* __restrict__ src,
                                                 int* __restrict__ cursor,
                                                 int* __restrict__ csr)
{
  int e = blockIdx.x * 256 + threadIdx.x;
  if (e < N_EDGES) {
    int p = atomicAdd(&cursor[src[e]], 1);
    csr[p] = e;
  }
}

// ---------------------------------------------------------------------------
// Fused per-node kernel (coalesced layout + 4-deep MLP) — proven ~45us.
// ---------------------------------------------------------------------------
__global__ __launch_bounds__(256) void node_attn_k(
    const float* __restrict__ QKVI, const float* __restrict__ Ef,
    const int* __restrict__ rowstart, const int* __restrict__ csr,
    const int* __restrict__ tgt, float* __restrict__ agg)
{
  __shared__ int   s_eid[MAXDEG];
  __shared__ int   s_tgt[MAXDEG];
  __shared__ float s_sc[HEADS][MAXDEGP];   // scores, then weights in-place
  __shared__ unsigned char s_alive[MAXDEG];
  __shared__ float s_self[8];
  __shared__ float s_wself[8];

  const float scl = 0.17677669529663687f;
  int i = blockIdx.x;
  int base = rowstart[i];
  int deg = rowstart[i + 1] - base;
  if (deg > MAXDEG) deg = MAXDEG;
  int tid = threadIdx.x;
  int w = tid >> 6, l = tid & 63;
  int h = tid >> 5, d = tid & 31;

  for (int t = tid; t < deg; t += 256) {
    int e = csr[base + t];
    s_eid[t] = e;
    s_tgt[t] = tgt[e];
  }
  __syncthreads();

  // Q_i: lane l holds dims 4l..4l+3 (head = l>>3)
  float4 q4 = *(const float4*)&QKVI[(size_t)i * 1024 + 4 * l];

  // self score (wave 0)
  if (w == 0) {
    float4 k4 = *(const float4*)&QKVI[(size_t)i * 1024 + 256 + 4 * l];
    float c = dot4(q4, k4);
    c += __shfl_xor(c, 1); c += __shfl_xor(c, 2); c += __shfl_xor(c, 4);
    if ((l & 7) == 0) s_self[l >> 3] = c * scl;
  }

  // edge logits: 4 edges per wave iteration, loads batched for MLP
  for (int t0 = w; t0 < deg; t0 += 16) {
    float4 ef[4], k4[4];
#pragma unroll
    for (int u = 0; u < 4; ++u) {
      int t = t0 + 4 * u;
      if (t < deg) {
        ef[u] = *(const float4*)&Ef[(size_t)s_eid[t] * 256 + 4 * l];
        k4[u] = *(const float4*)&QKVI[(size_t)s_tgt[t] * 1024 + 256 + 4 * l];
      }
    }
#pragma unroll
    for (int u = 0; u < 4; ++u) {
      int t = t0 + 4 * u;
      if (t < deg) {
        float c = dot4(q4, ef[u]) + dot4(ef[u], k4[u]) + dot4(q4, k4[u]);
        c += __shfl_xor(c, 1); c += __shfl_xor(c, 2); c += __shfl_xor(c, 4);
        if ((l & 7) == 0) s_sc[l >> 3][t] = c * scl;
      }
    }
  }

  // dedup (keep max eid per tgt), drop self-target
  for (int t = tid; t < deg; t += 256) {
    int tt = s_tgt[t], ee = s_eid[t];
    bool alive = (tt != i);
    if (alive)
      for (int u = 0; u < deg; ++u)
        if (s_tgt[u] == tt && s_eid[u] > ee) { alive = false; break; }
    s_alive[t] = alive ? 1 : 0;
  }
  __syncthreads();

  // softmax: 32 lanes per head; dead edges get weight exactly 0
  {
    float m = s_self[h];
    for (int t = d; t < deg; t += 32)
      if (s_alive[t]) m = fmaxf(m, s_sc[h][t]);
#pragma unroll
    for (int off = 16; off > 0; off >>= 1) m = fmaxf(m, __shfl_xor(m, off, 32));
    float lsum = 0.f;
    for (int t = d; t < deg; t += 32) {
      float wv = s_alive[t] ? expf(s_sc[h][t] - m) : 0.f;
      s_sc[h][t] = wv;
      lsum += wv;
    }
#pragma unroll
    for (int off = 16; off > 0; off >>= 1) lsum += __shfl_xor(lsum, off, 32);
    float wself = expf(s_self[h] - m);
    float inv = 1.f / (lsum + wself);
    if (d == 0) s_wself[h] = wself * inv;
    for (int t = d; t < deg; t += 32) s_sc[h][t] *= inv;
  }
  __syncthreads();

  // aggregate V: branch-free, 4-deep unrolled; col = tid -> coalesced
  int col = tid;
  float accv = s_wself[h] * QKVI[(size_t)i * 1024 + 512 + col];
  int t0 = 0;
  for (; t0 + 4 <= deg; t0 += 4) {
    float vl[4];
#pragma unroll
    for (int u = 0; u < 4; ++u)
      vl[u] = QKVI[(size_t)s_tgt[t0 + u] * 1024 + 512 + col];
#pragma unroll
    for (int u = 0; u < 4; ++u)
      accv += s_sc[h][t0 + u] * vl[u];
  }
  for (; t0 < deg; ++t0)
    accv += s_sc[h][t0] * QKVI[(size_t)s_tgt[t0] * 1024 + 512 + col];
  agg[(size_t)i * 256 + col] = accv;
}

// ---------------------------------------------------------------------------
// LayerNorm(x_proj + preo)
// ---------------------------------------------------------------------------
__global__ __launch_bounds__(256) void ln_k(
    const float* __restrict__ QKVI, const float* __restrict__ preo,
    const float* __restrict__ g, const float* __restrict__ b,
    float* __restrict__ out)
{
  int i = blockIdx.x, c = threadIdx.x;
  float v = QKVI[(size_t)i * 1024 + 768 + c] + preo[(size_t)i * 256 + c];
  float s1 = v, s2 = v * v;
#pragma unroll
  for (int off = 32; off > 0; off >>= 1) {
    s1 += __shfl_xor(s1, off, 64);
    s2 += __shfl_xor(s2, off, 64);
  }
  __shared__ float r1[4], r2[4];
  int w = c >> 6;
  if ((c & 63) == 0) { r1[w] = s1; r2[w] = s2; }
  __syncthreads();
  s1 = r1[0] + r1[1] + r1[2] + r1[3];
  s2 = r2[0] + r2[1] + r2[2] + r2[3];
  float mu  = s1 * (1.0f / 256.0f);
  float var = s2 * (1.0f / 256.0f) - mu * mu;
  out[(size_t)i * 256 + c] = (v - mu) * rsqrtf(var + 1e-5f) * g[c] + b[c];
}

// ---------------------------------------------------------------------------
extern "C" void kernel_launch(void* const* d_in, const int* in_sizes, int n_in,
                              void* d_out, int out_size, void* d_ws, size_t ws_size,
                              hipStream_t stream) {
  (void)in_sizes; (void)n_in; (void)out_size; (void)ws_size;
  const float* x  = (const float*)d_in[0];
  const int*   ei = (const int*)d_in[1];
  const float* ea = (const float*)d_in[2];
  const float* Wq = (const float*)d_in[3];  const float* bq = (const float*)d_in[4];
  const float* Wk = (const float*)d_in[5];  const float* bk = (const float*)d_in[6];
  const float* Wv = (const float*)d_in[7];  const float* bv = (const float*)d_in[8];
  const float* We = (const float*)d_in[9];  const float* be = (const float*)d_in[10];
  const float* Wo = (const float*)d_in[11]; const float* bo = (const float*)d_in[12];
  const float* Wi = (const float*)d_in[13]; const float* bi = (const float*)d_in[14];
  const float* lng = (const float*)d_in[15]; const float* lnb = (const float*)d_in[16];

  const int* src = ei;
  const int* tgt = ei + N_EDGES;

  char* ws = (char*)d_ws;
  u16*   WcatT   = (u16*)(ws + 0);              //  512 KB
  u16*   WeT     = (u16*)(ws + 524288);         //  128 KB
  u16*   WoT     = (u16*)(ws + 655360);         //  128 KB
  float* bcat    = (float*)(ws + 786432);       //    4 KB
  float* QKVI    = (float*)(ws + 790528);       //   16 MB
  int*   deg     = (int*)(ws + 17567744);       //   16 KB
  int*   rowstart= (int*)(ws + 17584128);       //   16.25 KB
  int*   cursor  = (int*)(ws + 17600768);       //   16 KB
  int*   csr     = (int*)(ws + 17617152);       //  512 KB
  float* agg     = (float*)(ws + 18141440);     //    4 MB
  float* preo    = (float*)(ws + 22335744);     //    4 MB

  float* outN = (float*)d_out;
  float* outE = (float*)d_out + (size_t)N_NODES * DIM;

  // weight prep + deg zeroing (blocks 1536..1551)
  prep_w_k<<<1552, 256, 0, stream>>>(Wq, Wk, Wv, Wi, We, Wo, bq, bk, bv, bi,
                                     WcatT, WeT, WoT, bcat, deg);

  hist_k<<<N_EDGES / 256, 256, 0, stream>>>(src, deg);
  scan_k<<<1, 1024, 0, stream>>>(deg, rowstart, cursor);
  scatter_k<<<N_EDGES / 256, 256, 0, stream>>>(src, cursor, csr);

  // merged: edge_out = ea @ We + be  AND  QKVI = x @ [Wq|Wk|Wv|Wi] + bcat
  gemm_all_k<<<2304, 256, 0, stream>>>(ea, WeT, be, outE, x, WcatT, bcat, QKVI);

  // fused logits + softmax + V aggregation
  node_attn_k<<<N_NODES, 256, 0, stream>>>(QKVI, outE, rowstart, csr, tgt, agg);

  // preo = agg @ Wo + bo
  gemm3_k<<<dim3(2, 32), 256, 0, stream>>>(agg, WoT, bo, preo, 256);

  ln_k<<<N_NODES, 256, 0, stream>>>(QKVI, preo, lng, lnb, outN);
}

// Round 16
// 175.765 us; speedup vs baseline: 1.6662x; 1.0268x over previous
//
#include <hip/hip_runtime.h>

#define N_NODES 4096
#define N_EDGES 131072
#define DIM     256
#define HEADS   8
#define HDIM    32
#define MAXDEG  320
#define MAXDEGP 321   // (321h+t)%32 = (h+t)%32 -> 8 heads hit distinct banks

typedef unsigned short u16;
typedef unsigned int   u32;

using f32x4  = __attribute__((ext_vector_type(4))) float;
using bf16x8 = __attribute__((ext_vector_type(8))) short;
using u16x4  = __attribute__((ext_vector_type(4))) unsigned short;
using u16x8  = __attribute__((ext_vector_type(8))) unsigned short;

__device__ __forceinline__ u16 f2bf(float f) {
  u32 u = __float_as_uint(f);
  u += 0x7fffu + ((u >> 16) & 1u);   // RNE
  return (u16)(u >> 16);
}

__device__ __forceinline__ float dot4(float4 a, float4 b) {
  return a.x * b.x + a.y * b.y + a.z * b.z + a.w * b.w;
}

// ---------------------------------------------------------------------------
// Weight prep (+ deg zeroing folded in: blocks 1536..1551)
// ---------------------------------------------------------------------------
__global__ __launch_bounds__(256) void prep_w_k(
    const float* __restrict__ Wq, const float* __restrict__ Wk,
    const float* __restrict__ Wv, const float* __restrict__ Wi,
    const float* __restrict__ We, const float* __restrict__ Wo,
    const float* __restrict__ bq, const float* __restrict__ bk,
    const float* __restrict__ bv, const float* __restrict__ bi,
    u16* __restrict__ WcatT, u16* __restrict__ WeT, u16* __restrict__ WoT,
    float* __restrict__ bcat, int* __restrict__ deg)
{
  int n = blockIdx.x;
  int k = threadIdx.x;
  if (n < 1024) {
    const float* W = (n < 256) ? Wq : (n < 512) ? Wk : (n < 768) ? Wv : Wi;
    int nn = n & 255;
    WcatT[(size_t)n * 256 + k] = f2bf(W[(size_t)k * 256 + nn]);
    if (k == 0) {
      const float* b = (n < 256) ? bq : (n < 512) ? bk : (n < 768) ? bv : bi;
      bcat[n] = b[nn];
    }
  } else if (n < 1280) {
    int nn = n - 1024;
    WeT[(size_t)nn * 256 + k] = f2bf(We[(size_t)k * 256 + nn]);
  } else if (n < 1536) {
    int nn = n - 1280;
    WoT[(size_t)nn * 256 + k] = f2bf(Wo[(size_t)k * 256 + nn]);
  } else {
    deg[(n - 1536) * 256 + k] = 0;
  }
}

// ---------------------------------------------------------------------------
// 128x256 GEMM body, 512 threads / 8 waves (2 row-halves x 4 col-quarters;
// per-wave 64x64 sub-tile identical to the proven gemm3 body). A-rows are
// read by EXACTLY ONE block (grid-x = 1) -> nontemporal A-loads are safe and
// keep L2/L3 clean so the C-stream (outE) stays L3-resident for node_attn.
// LDS dbuf (48KB), reg prefetch, lgkmcnt-only barrier, XOR swizzle.
// ---------------------------------------------------------------------------
__device__ __forceinline__ void gemm_big_body(
    const float* __restrict__ A, const u16* __restrict__ BT,
    const float* __restrict__ bias, float* __restrict__ C, int Nn,
    int m0, int nc0, u16 (&As)[2][128 * 32], u16 (&Bs)[2][256 * 32])
{
  const int tid = threadIdx.x;          // 0..511
  const int w = tid >> 6, l = tid & 63;
  const int wr = w >> 2, wc = w & 3;
  const int fr = l & 15, hi = l >> 4;

  f32x4 pa[2];
  u16x8 pb[2];
  f32x4 acc[4][4] = {};

  auto loadstep = [&](int kt) {
#pragma unroll
    for (int i = 0; i < 2; ++i) {
      int j = tid + 512 * i;            // 1024 float4 chunks: row=j>>3, col=(j&7)*4
      pa[i] = __builtin_nontemporal_load(
          (const f32x4*)(A + (size_t)(m0 + (j >> 3)) * 256 + kt * 32 + ((j & 7) << 2)));
    }
#pragma unroll
    for (int i = 0; i < 2; ++i) {
      int j = tid + 512 * i;            // 1024 u16x8 chunks: row=j>>2, col=(j&3)*8
      pb[i] = *(const u16x8*)(BT + (size_t)(nc0 + (j >> 2)) * 256 + kt * 32 + ((j & 3) << 3));
    }
  };
  auto storestep = [&](int buf) {
#pragma unroll
    for (int i = 0; i < 2; ++i) {
      int j = tid + 512 * i;
      int row = j >> 3;
      int c16 = (j & 7) >> 1, half = j & 1;
      int swc = (c16 + ((row >> 1) & 3)) & 3;
      u16x4 u;
      u.x = f2bf(pa[i][0]); u.y = f2bf(pa[i][1]); u.z = f2bf(pa[i][2]); u.w = f2bf(pa[i][3]);
      *(u16x4*)&As[buf][row * 32 + swc * 8 + half * 4] = u;
    }
#pragma unroll
    for (int i = 0; i < 2; ++i) {
      int j = tid + 512 * i;
      int row = j >> 2;
      int swc = ((j & 3) + ((row >> 1) & 3)) & 3;
      *(u16x8*)&Bs[buf][row * 32 + swc * 8] = pb[i];
    }
  };

  loadstep(0);
  storestep(0);

#pragma unroll
  for (int kt = 0; kt < 8; ++kt) {
    if (kt < 7) loadstep(kt + 1);
    __builtin_amdgcn_sched_barrier(0);
    asm volatile("s_waitcnt lgkmcnt(0)" ::: "memory");
    __builtin_amdgcn_s_barrier();
    __builtin_amdgcn_sched_barrier(0);
    const int cur = kt & 1;
    bf16x8 a[4], b[4];
#pragma unroll
    for (int mi = 0; mi < 4; ++mi) {
      int rA = wr * 64 + mi * 16 + fr;
      int swc = (hi + ((rA >> 1) & 3)) & 3;
      a[mi] = *(const bf16x8*)&As[cur][rA * 32 + swc * 8];
    }
#pragma unroll
    for (int ni = 0; ni < 4; ++ni) {
      int rB = wc * 64 + ni * 16 + fr;
      int swc = (hi + ((rB >> 1) & 3)) & 3;
      b[ni] = *(const bf16x8*)&Bs[cur][rB * 32 + swc * 8];
    }
#pragma unroll
    for (int mi = 0; mi < 4; ++mi)
#pragma unroll
      for (int ni = 0; ni < 4; ++ni)
        acc[mi][ni] = __builtin_amdgcn_mfma_f32_16x16x32_bf16(
            b[ni], a[mi], acc[mi][ni], 0, 0, 0);
    if (kt < 7) storestep((kt + 1) & 1);
  }

#pragma unroll
  for (int mi = 0; mi < 4; ++mi) {
    int row = m0 + wr * 64 + mi * 16 + fr;
#pragma unroll
    for (int ni = 0; ni < 4; ++ni) {
      int col = nc0 + wc * 64 + ni * 16 + hi * 4;
      float4 bv = *(const float4*)&bias[col];
      f32x4 v = acc[mi][ni];
      float4 o;
      o.x = v[0] + bv.x; o.y = v[1] + bv.y; o.z = v[2] + bv.z; o.w = v[3] + bv.w;
      *(float4*)&C[(size_t)row * Nn + col] = o;
    }
  }
}

// Merged dispatch: 1152 blocks = 1024 edge (128x256, ea read once) +
// 128 QKVI (128-row x 256-col tiles), every 9th block = QKVI.
__global__ __launch_bounds__(512) void gemm_all_k(
    const float* __restrict__ ea, const u16* __restrict__ WeT,
    const float* __restrict__ be, float* __restrict__ outE,
    const float* __restrict__ x, const u16* __restrict__ WcatT,
    const float* __restrict__ bcat, float* __restrict__ QKVI)
{
  __shared__ u16 As[2][128 * 32];
  __shared__ u16 Bs[2][256 * 32];
  int bid = blockIdx.x;
  int r = bid % 9, q = bid / 9;
  if (r < 8) {
    int j = q * 8 + r;                        // 0..1023
    gemm_big_body(ea, WeT, be, outE, 256, j * 128, 0, As, Bs);
  } else {
    // q 0..127: 32 row-tiles x 4 col-tiles of QKVI (4096 x 1024)
    gemm_big_body(x, WcatT, bcat, QKVI, 1024, (q >> 2) * 128, (q & 3) * 256, As, Bs);
  }
}

// Wo projection: preo = agg @ Wo + bo (agg read once -> nt loads)
__global__ __launch_bounds__(512) void gemm_wo_k(
    const float* __restrict__ agg, const u16* __restrict__ WoT,
    const float* __restrict__ bo, float* __restrict__ preo)
{
  __shared__ u16 As[2][128 * 32];
  __shared__ u16 Bs[2][256 * 32];
  gemm_big_body(agg, WoT, bo, preo, 256, blockIdx.x * 128, 0, As, Bs);
}

// ---------------------------------------------------------------------------
// CSR build
// ---------------------------------------------------------------------------
__global__ __launch_bounds__(256) void hist_k(const int* __restrict__ src, int* __restrict__ deg)
{
  int e = blockIdx.x * 256 + threadIdx.x;
  if (e < N_EDGES) atomicAdd(&deg[src[e]], 1);
}

__global__ __launch_bounds__(1024) void scan_k(const int* __restrict__ deg,
                                               int* __restrict__ rowstart,
                                               int* __restrict__ cursor)
{
  __shared__ int s[1024];
  int tid = threadIdx.x;
  int4 v = ((const int4*)deg)[tid];
  int sum = v.x + v.y + v.z + v.w;
  s[tid] = sum;
  __syncthreads();
  for (int off = 1; off < 1024; off <<= 1) {
    int t = (tid >= off) ? s[tid - off] : 0;
    __syncthreads();
    s[tid] += t;
    __syncthreads();
  }
  int excl = s[tid] - sum;
  int r0 = excl, r1 = excl + v.x, r2 = r1 + v.y, r3 = r2 + v.z;
  rowstart[4 * tid + 0] = r0; cursor[4 * tid + 0] = r0;
  rowstart[4 * tid + 1] = r1; cursor[4 * tid + 1] = r1;
  rowstart[4 * tid + 2] = r2; cursor[4 * tid + 2] = r2;
  rowstart[4 * tid + 3] = r3; cursor[4 * tid + 3] = r3;
  if (tid == 1023) rowstart[4096] = r3 + v.w;
}

__global__ __launch_bounds__(256) void scatter_k(const int* __restrict__ src,
                                                 int* __restrict__ cursor,
                                                 int* __restrict__ csr)
{
  int e = blockIdx.x * 256 + threadIdx.x;
  if (e < N_EDGES) {
    int p = atomicAdd(&cursor[src[e]], 1);
    csr[p] = e;
  }
}

// ---------------------------------------------------------------------------
// Fused per-node kernel (coalesced layout + 4-deep MLP) — proven ~45us;
// expected to accelerate if outE stays L3-resident (this round's hypothesis).
// ---------------------------------------------------------------------------
__global__ __launch_bounds__(256) void node_attn_k(
    const float* __restrict__ QKVI, const float* __restrict__ Ef,
    const int* __restrict__ rowstart, const int* __restrict__ csr,
    const int* __restrict__ tgt, float* __restrict__ agg)
{
  __shared__ int   s_eid[MAXDEG];
  __shared__ int   s_tgt[MAXDEG];
  __shared__ float s_sc[HEADS][MAXDEGP];   // scores, then weights in-place
  __shared__ unsigned char s_alive[MAXDEG];
  __shared__ float s_self[8];
  __shared__ float s_wself[8];

  const float scl = 0.17677669529663687f;
  int i = blockIdx.x;
  int base = rowstart[i];
  int deg = rowstart[i + 1] - base;
  if (deg > MAXDEG) deg = MAXDEG;
  int tid = threadIdx.x;
  int w = tid >> 6, l = tid & 63;
  int h = tid >> 5, d = tid & 31;

  for (int t = tid; t < deg; t += 256) {
    int e = csr[base + t];
    s_eid[t] = e;
    s_tgt[t] = tgt[e];
  }
  __syncthreads();

  // Q_i: lane l holds dims 4l..4l+3 (head = l>>3)
  float4 q4 = *(const float4*)&QKVI[(size_t)i * 1024 + 4 * l];

  // self score (wave 0)
  if (w == 0) {
    float4 k4 = *(const float4*)&QKVI[(size_t)i * 1024 + 256 + 4 * l];
    float c = dot4(q4, k4);
    c += __shfl_xor(c, 1); c += __shfl_xor(c, 2); c += __shfl_xor(c, 4);
    if ((l & 7) == 0) s_self[l >> 3] = c * scl;
  }

  // edge logits: 4 edges per wave iteration, loads batched for MLP
  for (int t0 = w; t0 < deg; t0 += 16) {
    float4 ef[4], k4[4];
#pragma unroll
    for (int u = 0; u < 4; ++u) {
      int t = t0 + 4 * u;
      if (t < deg) {
        ef[u] = *(const float4*)&Ef[(size_t)s_eid[t] * 256 + 4 * l];
        k4[u] = *(const float4*)&QKVI[(size_t)s_tgt[t] * 1024 + 256 + 4 * l];
      }
    }
#pragma unroll
    for (int u = 0; u < 4; ++u) {
      int t = t0 + 4 * u;
      if (t < deg) {
        float c = dot4(q4, ef[u]) + dot4(ef[u], k4[u]) + dot4(q4, k4[u]);
        c += __shfl_xor(c, 1); c += __shfl_xor(c, 2); c += __shfl_xor(c, 4);
        if ((l & 7) == 0) s_sc[l >> 3][t] = c * scl;
      }
    }
  }

  // dedup (keep max eid per tgt), drop self-target
  for (int t = tid; t < deg; t += 256) {
    int tt = s_tgt[t], ee = s_eid[t];
    bool alive = (tt != i);
    if (alive)
      for (int u = 0; u < deg; ++u)
        if (s_tgt[u] == tt && s_eid[u] > ee) { alive = false; break; }
    s_alive[t] = alive ? 1 : 0;
  }
  __syncthreads();

  // softmax: 32 lanes per head; dead edges get weight exactly 0
  {
    float m = s_self[h];
    for (int t = d; t < deg; t += 32)
      if (s_alive[t]) m = fmaxf(m, s_sc[h][t]);
#pragma unroll
    for (int off = 16; off > 0; off >>= 1) m = fmaxf(m, __shfl_xor(m, off, 32));
    float lsum = 0.f;
    for (int t = d; t < deg; t += 32) {
      float wv = s_alive[t] ? expf(s_sc[h][t] - m) : 0.f;
      s_sc[h][t] = wv;
      lsum += wv;
    }
#pragma unroll
    for (int off = 16; off > 0; off >>= 1) lsum += __shfl_xor(lsum, off, 32);
    float wself = expf(s_self[h] - m);
    float inv = 1.f / (lsum + wself);
    if (d == 0) s_wself[h] = wself * inv;
    for (int t = d; t < deg; t += 32) s_sc[h][t] *= inv;
  }
  __syncthreads();

  // aggregate V: branch-free, 4-deep unrolled; col = tid -> coalesced
  int col = tid;
  float accv = s_wself[h] * QKVI[(size_t)i * 1024 + 512 + col];
  int t0 = 0;
  for (; t0 + 4 <= deg; t0 += 4) {
    float vl[4];
#pragma unroll
    for (int u = 0; u < 4; ++u)
      vl[u] = QKVI[(size_t)s_tgt[t0 + u] * 1024 + 512 + col];
#pragma unroll
    for (int u = 0; u < 4; ++u)
      accv += s_sc[h][t0 + u] * vl[u];
  }
  for (; t0 < deg; ++t0)
    accv += s_sc[h][t0] * QKVI[(size_t)s_tgt[t0] * 1024 + 512 + col];
  agg[(size_t)i * 256 + col] = accv;
}

// ---------------------------------------------------------------------------
// LayerNorm(x_proj + preo)
// ---------------------------------------------------------------------------
__global__ __launch_bounds__(256) void ln_k(
    const float* __restrict__ QKVI, const float* __restrict__ preo,
    const float* __restrict__ g, const float* __restrict__ b,
    float* __restrict__ out)
{
  int i = blockIdx.x, c = threadIdx.x;
  float v = QKVI[(size_t)i * 1024 + 768 + c] + preo[(size_t)i * 256 + c];
  float s1 = v, s2 = v * v;
#pragma unroll
  for (int off = 32; off > 0; off >>= 1) {
    s1 += __shfl_xor(s1, off, 64);
    s2 += __shfl_xor(s2, off, 64);
  }
  __shared__ float r1[4], r2[4];
  int w = c >> 6;
  if ((c & 63) == 0) { r1[w] = s1; r2[w] = s2; }
  __syncthreads();
  s1 = r1[0] + r1[1] + r1[2] + r1[3];
  s2 = r2[0] + r2[1] + r2[2] + r2[3];
  float mu  = s1 * (1.0f / 256.0f);
  float var = s2 * (1.0f / 256.0f) - mu * mu;
  out[(size_t)i * 256 + c] = (v - mu) * rsqrtf(var + 1e-5f) * g[c] + b[c];
}

// ---------------------------------------------------------------------------
extern "C" void kernel_launch(void* const* d_in, const int* in_sizes, int n_in,
                              void* d_out, int out_size, void* d_ws, size_t ws_size,
                              hipStream_t stream) {
  (void)in_sizes; (void)n_in; (void)out_size; (void)ws_size;
  const float* x  = (const float*)d_in[0];
  const int*   ei = (const int*)d_in[1];
  const float* ea = (const float*)d_in[2];
  const float* Wq = (const float*)d_in[3];  const float* bq = (const float*)d_in[4];
  const float* Wk = (const float*)d_in[5];  const float* bk = (const float*)d_in[6];
  const float* Wv = (const float*)d_in[7];  const float* bv = (const float*)d_in[8];
  const float* We = (const float*)d_in[9];  const float* be = (const float*)d_in[10];
  const float* Wo = (const float*)d_in[11]; const float* bo = (const float*)d_in[12];
  const float* Wi = (const float*)d_in[13]; const float* bi = (const float*)d_in[14];
  const float* lng = (const float*)d_in[15]; const float* lnb = (const float*)d_in[16];

  const int* src = ei;
  const int* tgt = ei + N_EDGES;

  char* ws = (char*)d_ws;
  u16*   WcatT   = (u16*)(ws + 0);              //  512 KB
  u16*   WeT     = (u16*)(ws + 524288);         //  128 KB
  u16*   WoT     = (u16*)(ws + 655360);         //  128 KB
  float* bcat    = (float*)(ws + 786432);       //    4 KB
  float* QKVI    = (float*)(ws + 790528);       //   16 MB
  int*   deg     = (int*)(ws + 17567744);       //   16 KB
  int*   rowstart= (int*)(ws + 17584128);       //   16.25 KB
  int*   cursor  = (int*)(ws + 17600768);       //   16 KB
  int*   csr     = (int*)(ws + 17617152);       //  512 KB
  float* agg     = (float*)(ws + 18141440);     //    4 MB
  float* preo    = (float*)(ws + 22335744);     //    4 MB

  float* outN = (float*)d_out;
  float* outE = (float*)d_out + (size_t)N_NODES * DIM;

  // weight prep + deg zeroing (blocks 1536..1551)
  prep_w_k<<<1552, 256, 0, stream>>>(Wq, Wk, Wv, Wi, We, Wo, bq, bk, bv, bi,
                                     WcatT, WeT, WoT, bcat, deg);

  hist_k<<<N_EDGES / 256, 256, 0, stream>>>(src, deg);
  scan_k<<<1, 1024, 0, stream>>>(deg, rowstart, cursor);
  scatter_k<<<N_EDGES / 256, 256, 0, stream>>>(src, cursor, csr);

  // merged: edge_out = ea @ We + be  AND  QKVI = x @ [Wq|Wk|Wv|Wi] + bcat
  gemm_all_k<<<1152, 512, 0, stream>>>(ea, WeT, be, outE, x, WcatT, bcat, QKVI);

  // fused logits + softmax + V aggregation
  node_attn_k<<<N_NODES, 256, 0, stream>>>(QKVI, outE, rowstart, csr, tgt, agg);

  // preo = agg @ Wo + bo
  gemm_wo_k<<<N_NODES / 128, 512, 0, stream>>>(agg, WoT, bo, preo);

  ln_k<<<N_NODES, 256, 0, stream>>>(QKVI, preo, lng, lnb, outN);
}